// Round 12
// baseline (228.279 us; speedup 1.0000x reference)
//
#include <hip/hip_runtime.h>
#include <hip/hip_fp16.h>
#include <cmath>
#include <cstdint>

#define N_MET   100000
#define N_RXN   200000
#define E_SUB   400000
#define E_PROD  400000
#define HIDDEN  128
#define MSG_DIM 64
#define DT      0.01f
#define TGRID   16                     // cells per axis
#define TGP     17                     // points per axis
#define NPTS    (TGP * TGP)            // 289
#define CCH     16                     // uint4 chunk-regions per point (128 dims)
#define RPB     128                    // reactions per block (4 lanes/rxn)
#define RSB     512                    // threads per block
#define NGRP    ((N_RXN + RPB - 1) / RPB)   // 1563 rxn blocks
#define CAP     8                      // fixed bucket capacity per reaction
#define OVFMAX  4096
#define NBS2    ((E_SUB / 2 + 255) / 256)       // 782 sub-scatter blocks (2 edges/thr)
#define PBLK    ((E_PROD / 4 + RSB - 1) / RSB)  // 196 prod blocks in rxn launch

typedef _Float16 h2v __attribute__((ext_vector_type(2)));

__device__ __forceinline__ float dot2f(uint32_t a, uint32_t b, float c) {
#if __has_builtin(__builtin_amdgcn_fdot2)
    return __builtin_amdgcn_fdot2(__builtin_bit_cast(h2v, a),
                                  __builtin_bit_cast(h2v, b), c, false);
#else
    float2 fa = __half22float2(*(__half2*)&a);
    float2 fb = __half22float2(*(__half2*)&b);
    return fmaf(fa.x, fb.x, fmaf(fa.y, fb.y, c));
#endif
}

__device__ __forceinline__ float fast_tanh(float x) {
    float t = __expf(2.0f * x);
    return 1.0f - 2.0f * __builtin_amdgcn_rcpf(t + 1.0f);
}

__device__ __forceinline__ float softplus_f(float x) {
    return (x > 20.0f) ? x : log1pf(__expf(x));
}

// Heterogeneous blocks:
//   blocks [0, NPTS)            : table build (threads<128 active)
//   blocks [NPTS, NPTS+NBS2)    : substrate edge scatter, 2 edges/thread
//                                 (200K threads: latency stage needs waves, not
//                                  per-thread MLP — 8/thr was 0.76 waves/SIMD)
// Table layout == LDS layout (identity staging): half ((c*NPTS+p)*8 + h).
__global__ void __launch_bounds__(256)
prep_all(const float* __restrict__ W1, const float* __restrict__ b1,
         const float* __restrict__ W2, const float* __restrict__ b2,
         const float* __restrict__ V1, __half* __restrict__ TGh,
         const int* __restrict__ rxn_sub, const int* __restrict__ met_sub,
         const float* __restrict__ sto_sub, const float* __restrict__ x,
         int* __restrict__ cnt,
         uint4* __restrict__ recs,
         uint4* __restrict__ ovf, uint2* __restrict__ ovf2,
         int* __restrict__ ovf_cnt) {
    __shared__ float h_s[HIDDEN];
    __shared__ float msg_s[MSG_DIM];
    int bid = blockIdx.x;
    int tid = threadIdx.x;
    if (bid < NPTS) {
        // ---- table build ----
        int p = bid;
        int ia = p / TGP, ib = p % TGP;
        float a = (float)ia * (1.0f / TGRID);
        float b = 0.5f + (float)ib * (1.0f / TGRID);
        if (tid < HIDDEN)
            h_s[tid] = tanhf(fmaf(a, W1[tid], fmaf(b, W1[HIDDEN + tid], b1[tid])));
        __syncthreads();
        if (tid < MSG_DIM) {
            float acc = b2[tid];
            #pragma unroll 4
            for (int j = 0; j < HIDDEN; ++j)
                acc = fmaf(h_s[j], W2[j * MSG_DIM + tid], acc);
            msg_s[tid] = acc;
        }
        __syncthreads();
        if (tid < HIDDEN) {
            float g = 0.0f;
            #pragma unroll 4
            for (int m = 0; m < MSG_DIM; ++m)
                g = fmaf(msg_s[m], V1[m * HIDDEN + tid], g);
            int c = tid >> 3;
            int h = tid & 7;
            TGh[((size_t)(c * NPTS + p) * 8) + h] = __float2half(g);
        }
        return;
    }
    // ---- substrate scatter: 2 edges per thread, vectorized reads ----
    int i2 = (bid - NPTS) * 256 + tid;            // 2-edge group index
    if (i2 >= E_SUB / 2) return;
    int2   rr = ((const int2*)rxn_sub)[i2];
    int2   mm = ((const int2*)met_sub)[i2];
    float2 ss = ((const float2*)sto_sub)[i2];
    #pragma unroll
    for (int u = 0; u < 2; ++u) {
        int r  = (&rr.x)[u];
        int me = (&mm.x)[u];
        float se  = (&ss.x)[u];
        float ae  = x[me * 8 + 3];
        float ext = x[me * 8 + 4];
        float fa = ae * (float)TGRID;
        float fb = (se - 0.5f) * (float)TGRID;
        int ia = (int)fa; ia = ia < 0 ? 0 : (ia > TGRID - 1 ? TGRID - 1 : ia);
        int ib = (int)fb; ib = ib < 0 ? 0 : (ib > TGRID - 1 ? TGRID - 1 : ib);
        float wa = fa - (float)ia, wb = fb - (float)ib;
        float ua = 1.0f - wa, ub = 1.0f - wb;
        __half2 hA = __floats2half2_rn(ua * ub, ua * wb);   // w00, w01
        __half2 hB = __floats2half2_rn(wa * ub, wa * wb);   // w10, w11
        __half2 hS = __floats2half2_rn(se, ext);            // sto, ext
        int cell = ia * TGP + ib;                            // point space, <= 288
        int slot = atomicAdd(&cnt[r], 1);
        uint4 rec;
        rec.y = *(uint32_t*)&hA;
        rec.z = *(uint32_t*)&hB;
        rec.w = *(uint32_t*)&hS;
        if (slot < CAP) {
            rec.x = (uint32_t)cell | ((uint32_t)me << 10);
            recs[(size_t)r * CAP + slot] = rec;
        } else {
            int o = atomicAdd(ovf_cnt, 1);
            if (o < OVFMAX) {
                rec.x = (uint32_t)cell | ((uint32_t)r << 10);
                ovf[o] = rec;
                ovf2[o] = make_uint2((uint32_t)me, 0u);
            }
        }
    }
}

// Heterogeneous launch:
//   blocks [0, PBLK)        : product-CSR build (4 edges/thread)
//   blocks [PBLK, +NGRP)    : reaction compute, 4 lanes/rxn (z[32]/lane).
// Lane q owns chunks 4q..4q+3 (dims 32q..32q+31). Direct LDS staging.
__global__ void __launch_bounds__(RSB, 4)
rxn_quad(const int* __restrict__ cnt, const uint4* __restrict__ recs,
         const uint4* __restrict__ ovf, const uint2* __restrict__ ovf2,
         const int* __restrict__ ovf_cnt, const uint32_t* __restrict__ TG,
         const float* __restrict__ c1, const float* __restrict__ V2,
         const float* __restrict__ c2, const float* __restrict__ log_k,
         const int* __restrict__ rxn_prod, const int* __restrict__ met_prod,
         const float* __restrict__ sto_prod,
         int* __restrict__ pcnt, uint2* __restrict__ precs,
         uint4* __restrict__ povf, int* __restrict__ povf_cnt,
         float* __restrict__ v_out, float* __restrict__ tot) {
    __shared__ uint4 tbl4[CCH * NPTS];            // 73,984 B table
    __shared__ float c1s[HIDDEN];
    __shared__ float v2s[HIDDEN];
    __shared__ int sorted_s[RPB];
    __shared__ int h16[16];
    int t = threadIdx.x;
    if (blockIdx.x < PBLK) {
        // ---- product scatter: 4 edges per thread ----
        int i4 = blockIdx.x * RSB + t;            // int4 index
        if (i4 >= E_PROD / 4) return;
        int4   rr = ((const int4*)rxn_prod)[i4];
        int4   mm = ((const int4*)met_prod)[i4];
        float4 ss = ((const float4*)sto_prod)[i4];
        #pragma unroll
        for (int u = 0; u < 4; ++u) {
            int r  = (&rr.x)[u];
            int me = (&mm.x)[u];
            float sp = (&ss.x)[u];
            int slot = atomicAdd(&pcnt[r], 1);
            if (slot < CAP) {
                precs[(size_t)r * CAP + slot] = make_uint2((uint32_t)me, __float_as_uint(sp));
            } else {
                int o = atomicAdd(povf_cnt, 1);
                if (o < OVFMAX)
                    povf[o] = make_uint4((uint32_t)r, (uint32_t)me, __float_as_uint(sp), 0u);
            }
        }
        return;
    }
    int rbase = (blockIdx.x - PBLK) * RPB;
    int nval = N_RXN - rbase; if (nval > RPB) nval = RPB;

    // ---- in-block counting sort by edge count ----
    if (t < 16) h16[t] = 0;
    if (t < HIDDEN) { c1s[t] = c1[t]; v2s[t] = V2[t]; }
    __syncthreads();
    int n1 = -1, k1 = 0;
    if (t < nval) {
        n1 = cnt[rbase + t];
        k1 = n1 > 15 ? 15 : n1;
        atomicAdd(&h16[k1], 1);
    }
    __syncthreads();
    if (t == 0) {
        int acc = 0;
        #pragma unroll
        for (int b = 0; b < 16; ++b) { int c = h16[b]; h16[b] = acc; acc += c; }
    }
    __syncthreads();
    if (n1 >= 0) sorted_s[atomicAdd(&h16[k1], 1)] = t;

    // ---- stage full table (identity-coalesced, direct global->LDS) ----
    {
        const uint4* src = (const uint4*)TG;
        for (int i = t; i < CCH * NPTS; i += RSB) tbl4[i] = src[i];
    }
    __syncthreads();

    int slot = t >> 2, q = t & 3;
    if (slot >= nval) return;
    int r = rbase + sorted_s[slot];
    int n = cnt[r];
    int nmain = n < CAP ? n : CAP;
    const int cb0 = q * 4;                        // this lane's chunk base
    float z[32];
    #pragma unroll
    for (int j = 0; j < 32; ++j) z[j] = c1s[q * 32 + j];
    float eacc = 0.0f;
    const uint4* rrec = recs + (size_t)r * CAP;
    for (int e = 0; e < nmain; ++e) {
        uint4 rec = rrec[e];                      // 4 lanes: same line (broadcast)
        int cell = (int)(rec.x & 1023);
        float2 sx = __half22float2(*(__half2*)&rec.w);   // sto, ext
        eacc += sx.y;
        const uint4* base = tbl4 + cb0 * NPTS + cell;    // imm offsets small
        #pragma unroll
        for (int c = 0; c < 4; ++c) {
            uint4 A = base[c * NPTS];
            uint4 B = base[c * NPTS + 1];
            uint4 C = base[c * NPTS + TGP];
            uint4 D = base[c * NPTS + TGP + 1];
            #pragma unroll
            for (int u = 0; u < 4; ++u) {
                uint32_t au = (&A.x)[u], bu = (&B.x)[u], cu = (&C.x)[u], du = (&D.x)[u];
                uint32_t ab0 = __builtin_amdgcn_perm(bu, au, 0x05040100u); // (Aj ,Bj )
                uint32_t ab1 = __builtin_amdgcn_perm(bu, au, 0x07060302u); // (Aj1,Bj1)
                uint32_t cd0 = __builtin_amdgcn_perm(du, cu, 0x05040100u); // (Cj ,Dj )
                uint32_t cd1 = __builtin_amdgcn_perm(du, cu, 0x07060302u); // (Cj1,Dj1)
                int j = c * 8 + 2 * u;
                z[j]     = dot2f(ab0, rec.y, dot2f(cd0, rec.z, z[j]));
                z[j + 1] = dot2f(ab1, rec.y, dot2f(cd1, rec.z, z[j + 1]));
            }
        }
    }
    int oc = 0;
    if (n > CAP) {                           // ultra-rare overflow path
        oc = *ovf_cnt; if (oc > OVFMAX) oc = OVFMAX;
        for (int o = 0; o < oc; ++o) {
            uint4 rec = ovf[o];
            if ((int)(rec.x >> 10) != r) continue;
            int cell = (int)(rec.x & 1023);
            float2 sx = __half22float2(*(__half2*)&rec.w);
            eacc += sx.y;
            const uint4* base = tbl4 + cb0 * NPTS + cell;
            #pragma unroll
            for (int c = 0; c < 4; ++c) {
                uint4 A = base[c * NPTS];
                uint4 B = base[c * NPTS + 1];
                uint4 C = base[c * NPTS + TGP];
                uint4 D = base[c * NPTS + TGP + 1];
                #pragma unroll
                for (int u = 0; u < 4; ++u) {
                    uint32_t au = (&A.x)[u], bu = (&B.x)[u], cu = (&C.x)[u], du = (&D.x)[u];
                    uint32_t ab0 = __builtin_amdgcn_perm(bu, au, 0x05040100u);
                    uint32_t ab1 = __builtin_amdgcn_perm(bu, au, 0x07060302u);
                    uint32_t cd0 = __builtin_amdgcn_perm(du, cu, 0x05040100u);
                    uint32_t cd1 = __builtin_amdgcn_perm(du, cu, 0x07060302u);
                    int j = c * 8 + 2 * u;
                    z[j]     = dot2f(ab0, rec.y, dot2f(cd0, rec.z, z[j]));
                    z[j + 1] = dot2f(ab1, rec.y, dot2f(cd1, rec.z, z[j + 1]));
                }
            }
        }
    }
    float pp = 0.0f;
    #pragma unroll
    for (int j = 0; j < 32; ++j)
        pp = fmaf(v2s[q * 32 + j], fast_tanh(z[j]), pp);
    pp += __shfl_xor(pp, 1);
    pp += __shfl_xor(pp, 2);                 // all 4 lanes hold the full sum
    // ---- finalize v + consumption scatter ----
    float em = eacc / (float)(n > 0 ? n : 1);
    float bv = softplus_f(pp + c2[0]);
    float k  = __expf(log_k[r] * 2.302585092994046f);
    float vr = k * em * bv;
    if (q == 0) v_out[r] = vr;
    float w = vr * DT;
    for (int e = q; e < nmain; e += 4) {
        uint4 rec = rrec[e];
        float2 sx = __half22float2(*(__half2*)&rec.w);
        atomicAdd(&tot[rec.x >> 10], sx.x * w);
    }
    if (n > CAP && q == 0) {
        for (int o = 0; o < oc; ++o) {
            if ((int)(ovf[o].x >> 10) != r) continue;
            float2 sx = __half22float2(*(__half2*)&ovf[o].w);
            atomicAdd(&tot[ovf2[o].x], sx.x * w);
        }
    }
}

// Slot-parallel scale+scatter: 8 lanes per reaction, lane l owns rec slot l.
__global__ void __launch_bounds__(256)
scale8(const int* __restrict__ cnt, const int* __restrict__ pcnt,
       const uint4* __restrict__ recs, const uint2* __restrict__ precs,
       const uint4* __restrict__ ovf, const uint2* __restrict__ ovf2,
       const uint4* __restrict__ povf,
       const int* __restrict__ ovf_cnt, const int* __restrict__ povf_cnt,
       const float* __restrict__ x, const float* __restrict__ tot,
       const float* __restrict__ v, float* __restrict__ out) {
    int t = blockIdx.x * blockDim.x + threadIdx.x;
    int r = t >> 3, l = t & 7;
    if (r >= N_RXN) return;
    int n = cnt[r];
    int nmain = n < CAP ? n : CAP;
    uint4 rec = recs[(size_t)r * CAP + l];        // coalesced: 8 lanes = 128B line
    uint32_t m = rec.x >> 10;
    float sto = 0.0f;
    float cand = 1.0f;
    if (l < nmain) {
        float2 sx = __half22float2(*(__half2*)&rec.w);
        sto = sx.x;
        float tc = tot[m];
        if (tc > 1e-12f) cand = fminf(x[m * 8 + 3] / tc, 1.0f);
    }
    int oc = 0;
    if (n > CAP) {                                 // rare overflow: lane 0 serial
        oc = *ovf_cnt; if (oc > OVFMAX) oc = OVFMAX;
        if (l == 0) {
            for (int o = 0; o < oc; ++o) {
                if ((int)(ovf[o].x >> 10) != r) continue;
                uint32_t mm = ovf2[o].x;
                float tc = tot[mm];
                if (tc > 1e-12f) cand = fminf(cand, fminf(x[mm * 8 + 3] / tc, 1.0f));
            }
        }
    }
    cand = fminf(cand, __shfl_xor(cand, 1));
    cand = fminf(cand, __shfl_xor(cand, 2));
    cand = fminf(cand, __shfl_xor(cand, 4));       // all 8 lanes: group min
    float vr = v[r] * cand;
    if (l < nmain) atomicAdd(&out[m], -sto * vr);  // substrate contribution
    if (n > CAP && l == 0) {
        for (int o = 0; o < oc; ++o) {
            if ((int)(ovf[o].x >> 10) != r) continue;
            float2 sx = __half22float2(*(__half2*)&ovf[o].w);
            atomicAdd(&out[ovf2[o].x], -sx.x * vr);
        }
    }
    int np = pcnt[r];
    int npm = np < CAP ? np : CAP;
    if (l < npm) {
        uint2 pr = precs[(size_t)r * CAP + l];     // coalesced: 8 lanes = 64B
        atomicAdd(&out[pr.x], __uint_as_float(pr.y) * vr);
    }
    if (np > CAP && l == 0) {
        int oc2 = *povf_cnt; if (oc2 > OVFMAX) oc2 = OVFMAX;
        for (int o = 0; o < oc2; ++o) {
            if ((int)povf[o].x != r) continue;
            atomicAdd(&out[povf[o].y], __uint_as_float(povf[o].z) * vr);
        }
    }
}

extern "C" void kernel_launch(void* const* d_in, const int* in_sizes, int n_in,
                              void* d_out, int out_size, void* d_ws, size_t ws_size,
                              hipStream_t stream) {
    const float* x        = (const float*)d_in[0];
    const int*   met_sub  = (const int*)d_in[1];
    const int*   rxn_sub  = (const int*)d_in[2];
    const float* sto_sub  = (const float*)d_in[3];
    const int*   met_prod = (const int*)d_in[4];
    const int*   rxn_prod = (const int*)d_in[5];
    const float* sto_prod = (const float*)d_in[6];
    const float* W1       = (const float*)d_in[7];
    const float* b1       = (const float*)d_in[8];
    const float* W2       = (const float*)d_in[9];
    const float* b2       = (const float*)d_in[10];
    const float* V1       = (const float*)d_in[11];
    const float* c1       = (const float*)d_in[12];
    const float* V2       = (const float*)d_in[13];
    const float* c2       = (const float*)d_in[14];
    const float* log_k    = (const float*)d_in[15];

    uint4* recs    = (uint4*)d_ws;                    // N_RXN*CAP        25.6 MB
    uint2* precs   = (uint2*)(recs + (size_t)N_RXN * CAP);   // N_RXN*CAP 12.8 MB
    uint4* ovf     = (uint4*)(precs + (size_t)N_RXN * CAP);  // OVFMAX
    uint2* ovf2    = (uint2*)(ovf + OVFMAX);
    uint4* povf    = (uint4*)(ovf2 + OVFMAX);
    int*   cnt     = (int*)(povf + OVFMAX);           // ---- zero region start ----
    int*   pcnt    = cnt + N_RXN;
    float* tot     = (float*)(pcnt + N_RXN);
    int*   ovf_cnt = (int*)(tot + N_MET);
    int*   povf_cnt = ovf_cnt + 1;                    // ---- zero region end ----
    float* v       = (float*)(povf_cnt + 3);
    uint32_t* TG   = (uint32_t*)(v + N_RXN);          // CCH*NPTS uint4 = 73,984 B
    float* outf = (float*)d_out;

    size_t zbytes = (size_t)(2 * N_RXN + N_MET + 4) * 4;   // cnt,pcnt,tot,counters
    hipMemsetAsync(cnt, 0, zbytes, stream);
    hipMemsetAsync(outf, 0, (size_t)N_MET * 4, stream);

    prep_all<<<NPTS + NBS2, 256, 0, stream>>>(
        W1, b1, W2, b2, V1, (__half*)TG,
        rxn_sub, met_sub, sto_sub, x,
        cnt, recs, ovf, ovf2, ovf_cnt);
    rxn_quad<<<PBLK + NGRP, RSB, 0, stream>>>(
        cnt, recs, ovf, ovf2, ovf_cnt, TG,
        c1, V2, c2, log_k,
        rxn_prod, met_prod, sto_prod,
        pcnt, precs, povf, povf_cnt,
        v, tot);
    scale8<<<((size_t)N_RXN * 8 + 255) / 256, 256, 0, stream>>>(
        cnt, pcnt, recs, precs, ovf, ovf2, povf, ovf_cnt, povf_cnt,
        x, tot, v, outf);
}

// Round 13
// 223.604 us; speedup vs baseline: 1.0209x; 1.0209x over previous
//
#include <hip/hip_runtime.h>
#include <hip/hip_fp16.h>
#include <cmath>
#include <cstdint>

#define N_MET   100000
#define N_RXN   200000
#define E_SUB   400000
#define E_PROD  400000
#define HIDDEN  128
#define MSG_DIM 64
#define DT      0.01f
#define TGRID   16                     // cells per axis
#define TGP     17                     // points per axis
#define NPTS    (TGP * TGP)            // 289
#define CCH     16                     // uint4 chunk-regions per point (128 dims)
#define HCH     8                      // chunks staged per pass (64 dims)
#define RPB     128                    // reactions per block (4 lanes/rxn)
#define RSB     512                    // threads per block
#define NGRP    ((N_RXN + RPB - 1) / RPB)   // 1563 rxn blocks
#define CAP     8                      // fixed bucket capacity per reaction
#define OVFMAX  4096
#define NBS8    ((E_SUB / 8 + 255) / 256)       // 196 sub-scatter blocks (8 edges/thr)
#define PBLK    ((E_PROD / 4 + RSB - 1) / RSB)  // 196 prod blocks in rxn launch

typedef _Float16 h2v __attribute__((ext_vector_type(2)));

__device__ __forceinline__ float dot2f(uint32_t a, uint32_t b, float c) {
#if __has_builtin(__builtin_amdgcn_fdot2)
    return __builtin_amdgcn_fdot2(__builtin_bit_cast(h2v, a),
                                  __builtin_bit_cast(h2v, b), c, false);
#else
    float2 fa = __half22float2(*(__half2*)&a);
    float2 fb = __half22float2(*(__half2*)&b);
    return fmaf(fa.x, fb.x, fmaf(fa.y, fb.y, c));
#endif
}

__device__ __forceinline__ float fast_tanh(float x) {
    float t = __expf(2.0f * x);
    return 1.0f - 2.0f * __builtin_amdgcn_rcpf(t + 1.0f);
}

__device__ __forceinline__ float softplus_f(float x) {
    return (x > 20.0f) ? x : log1pf(__expf(x));
}

// Heterogeneous blocks:
//   blocks [0, NPTS)            : table build (threads<128 active)
//   blocks [NPTS, NPTS+NBS8)    : substrate edge scatter, 8 edges/thread
// Table layout == LDS layout (identity staging): half ((c*NPTS+p)*8 + h).
__global__ void __launch_bounds__(256)
prep_all(const float* __restrict__ W1, const float* __restrict__ b1,
         const float* __restrict__ W2, const float* __restrict__ b2,
         const float* __restrict__ V1, __half* __restrict__ TGh,
         const int* __restrict__ rxn_sub, const int* __restrict__ met_sub,
         const float* __restrict__ sto_sub, const float* __restrict__ x,
         int* __restrict__ cnt,
         uint4* __restrict__ recs,
         uint4* __restrict__ ovf, uint2* __restrict__ ovf2,
         int* __restrict__ ovf_cnt) {
    __shared__ float h_s[HIDDEN];
    __shared__ float msg_s[MSG_DIM];
    int bid = blockIdx.x;
    int tid = threadIdx.x;
    if (bid < NPTS) {
        // ---- table build ----
        int p = bid;
        int ia = p / TGP, ib = p % TGP;
        float a = (float)ia * (1.0f / TGRID);
        float b = 0.5f + (float)ib * (1.0f / TGRID);
        if (tid < HIDDEN)
            h_s[tid] = tanhf(fmaf(a, W1[tid], fmaf(b, W1[HIDDEN + tid], b1[tid])));
        __syncthreads();
        if (tid < MSG_DIM) {
            float acc = b2[tid];
            #pragma unroll 4
            for (int j = 0; j < HIDDEN; ++j)
                acc = fmaf(h_s[j], W2[j * MSG_DIM + tid], acc);
            msg_s[tid] = acc;
        }
        __syncthreads();
        if (tid < HIDDEN) {
            float g = 0.0f;
            #pragma unroll 4
            for (int m = 0; m < MSG_DIM; ++m)
                g = fmaf(msg_s[m], V1[m * HIDDEN + tid], g);
            int c = tid >> 3;
            int h = tid & 7;
            TGh[((size_t)(c * NPTS + p) * 8) + h] = __float2half(g);
        }
        return;
    }
    // ---- substrate scatter: 8 edges per thread, vectorized reads ----
    int i8 = (bid - NPTS) * 256 + tid;            // 8-edge group index
    if (i8 >= E_SUB / 8) return;
    int4   rr0 = ((const int4*)rxn_sub)[2 * i8],     rr1 = ((const int4*)rxn_sub)[2 * i8 + 1];
    int4   mm0 = ((const int4*)met_sub)[2 * i8],     mm1 = ((const int4*)met_sub)[2 * i8 + 1];
    float4 ss0 = ((const float4*)sto_sub)[2 * i8],   ss1 = ((const float4*)sto_sub)[2 * i8 + 1];
    #pragma unroll
    for (int u = 0; u < 8; ++u) {
        int r  = (u < 4) ? (&rr0.x)[u] : (&rr1.x)[u - 4];
        int me = (u < 4) ? (&mm0.x)[u] : (&mm1.x)[u - 4];
        float se  = (u < 4) ? (&ss0.x)[u] : (&ss1.x)[u - 4];
        float ae  = x[me * 8 + 3];
        float ext = x[me * 8 + 4];
        float fa = ae * (float)TGRID;
        float fb = (se - 0.5f) * (float)TGRID;
        int ia = (int)fa; ia = ia < 0 ? 0 : (ia > TGRID - 1 ? TGRID - 1 : ia);
        int ib = (int)fb; ib = ib < 0 ? 0 : (ib > TGRID - 1 ? TGRID - 1 : ib);
        float wa = fa - (float)ia, wb = fb - (float)ib;
        float ua = 1.0f - wa, ub = 1.0f - wb;
        __half2 hA = __floats2half2_rn(ua * ub, ua * wb);   // w00, w01
        __half2 hB = __floats2half2_rn(wa * ub, wa * wb);   // w10, w11
        __half2 hS = __floats2half2_rn(se, ext);            // sto, ext
        int cell = ia * TGP + ib;                            // point space, <= 288
        int slot = atomicAdd(&cnt[r], 1);
        uint4 rec;
        rec.y = *(uint32_t*)&hA;
        rec.z = *(uint32_t*)&hB;
        rec.w = *(uint32_t*)&hS;
        if (slot < CAP) {
            rec.x = (uint32_t)cell | ((uint32_t)me << 10);
            recs[(size_t)r * CAP + slot] = rec;
        } else {
            int o = atomicAdd(ovf_cnt, 1);
            if (o < OVFMAX) {
                rec.x = (uint32_t)cell | ((uint32_t)r << 10);
                ovf[o] = rec;
                ovf2[o] = make_uint2((uint32_t)me, 0u);
            }
        }
    }
}

// Heterogeneous launch:
//   blocks [0, PBLK)        : product-CSR build (4 edges/thread)
//   blocks [PBLK, +NGRP)    : reaction compute, TWO-PASS half-table.
// Pass p stages chunks 8p..8p+7 (37 KB) into ONE LDS buffer; lane q owns
// local chunks {2q, 2q+1} = dims 64p+16q .. +15 (z[16]/lane). Halved LDS ->
// 3 blocks/CU (24 waves/CU vs 16). All barriers block-local; inactive lanes
// predicated (never skip a barrier).
__global__ void __launch_bounds__(RSB, 6)
rxn_quad(const int* __restrict__ cnt, const uint4* __restrict__ recs,
         const uint4* __restrict__ ovf, const uint2* __restrict__ ovf2,
         const int* __restrict__ ovf_cnt, const uint32_t* __restrict__ TG,
         const float* __restrict__ c1, const float* __restrict__ V2,
         const float* __restrict__ c2, const float* __restrict__ log_k,
         const int* __restrict__ rxn_prod, const int* __restrict__ met_prod,
         const float* __restrict__ sto_prod,
         int* __restrict__ pcnt, uint2* __restrict__ precs,
         uint4* __restrict__ povf, int* __restrict__ povf_cnt,
         float* __restrict__ v_out, float* __restrict__ tot) {
    __shared__ uint4 tbl4[HCH * NPTS];            // 36,992 B half-table
    __shared__ float c1s[HIDDEN];
    __shared__ float v2s[HIDDEN];
    __shared__ int sorted_s[RPB];
    __shared__ int h16[16];
    int t = threadIdx.x;
    if (blockIdx.x < PBLK) {
        // ---- product scatter: 4 edges per thread ----
        int i4 = blockIdx.x * RSB + t;            // int4 index
        if (i4 >= E_PROD / 4) return;
        int4   rr = ((const int4*)rxn_prod)[i4];
        int4   mm = ((const int4*)met_prod)[i4];
        float4 ss = ((const float4*)sto_prod)[i4];
        #pragma unroll
        for (int u = 0; u < 4; ++u) {
            int r  = (&rr.x)[u];
            int me = (&mm.x)[u];
            float sp = (&ss.x)[u];
            int slot = atomicAdd(&pcnt[r], 1);
            if (slot < CAP) {
                precs[(size_t)r * CAP + slot] = make_uint2((uint32_t)me, __float_as_uint(sp));
            } else {
                int o = atomicAdd(povf_cnt, 1);
                if (o < OVFMAX)
                    povf[o] = make_uint4((uint32_t)r, (uint32_t)me, __float_as_uint(sp), 0u);
            }
        }
        return;
    }
    int rbase = (blockIdx.x - PBLK) * RPB;
    int nval = N_RXN - rbase; if (nval > RPB) nval = RPB;

    // ---- in-block counting sort by edge count ----
    if (t < 16) h16[t] = 0;
    if (t < HIDDEN) { c1s[t] = c1[t]; v2s[t] = V2[t]; }
    __syncthreads();
    int n1 = -1, k1 = 0;
    if (t < nval) {
        n1 = cnt[rbase + t];
        k1 = n1 > 15 ? 15 : n1;
        atomicAdd(&h16[k1], 1);
    }
    __syncthreads();
    if (t == 0) {
        int acc = 0;
        #pragma unroll
        for (int b = 0; b < 16; ++b) { int c = h16[b]; h16[b] = acc; acc += c; }
    }
    __syncthreads();
    if (n1 >= 0) sorted_s[atomicAdd(&h16[k1], 1)] = t;
    // (sorted_s reads happen after the pass-0 post-staging barrier below)

    int slot = t >> 2, q = t & 3;
    int r = -1, n = 0, nmain = 0, oc = 0;
    const uint4* rrec = nullptr;
    float pp = 0.0f, eacc = 0.0f;

    #pragma unroll 1
    for (int pass = 0; pass < 2; ++pass) {
        if (pass) __syncthreads();               // pass-0 reads of tbl4 done
        // ---- stage this pass's half-table (identity-coalesced) ----
        {
            const uint4* src = (const uint4*)TG + pass * (HCH * NPTS);
            for (int i = t; i < HCH * NPTS; i += RSB) tbl4[i] = src[i];
        }
        __syncthreads();                         // table (and sorted_s) ready
        if (pass == 0 && slot < nval) {
            r = rbase + sorted_s[slot];
            n = cnt[r];
            nmain = n < CAP ? n : CAP;
            rrec = recs + (size_t)r * CAP;
        }
        if (r >= 0) {
            float z[16];
            #pragma unroll
            for (int j = 0; j < 16; ++j) z[j] = c1s[pass * 64 + q * 16 + j];
            for (int e = 0; e < nmain; ++e) {
                uint4 rec = rrec[e];             // 4 lanes: same line (broadcast)
                int cell = (int)(rec.x & 1023);
                if (pass == 0) {
                    float2 sx = __half22float2(*(__half2*)&rec.w);
                    eacc += sx.y;
                }
                #pragma unroll
                for (int lc2 = 0; lc2 < 2; ++lc2) {
                    const uint4* base = tbl4 + (2 * q + lc2) * NPTS + cell;
                    uint4 A = base[0];
                    uint4 B = base[1];
                    uint4 C = base[TGP];
                    uint4 D = base[TGP + 1];
                    #pragma unroll
                    for (int u = 0; u < 4; ++u) {
                        uint32_t au = (&A.x)[u], bu = (&B.x)[u], cu = (&C.x)[u], du = (&D.x)[u];
                        uint32_t ab0 = __builtin_amdgcn_perm(bu, au, 0x05040100u); // (Aj ,Bj )
                        uint32_t ab1 = __builtin_amdgcn_perm(bu, au, 0x07060302u); // (Aj1,Bj1)
                        uint32_t cd0 = __builtin_amdgcn_perm(du, cu, 0x05040100u); // (Cj ,Dj )
                        uint32_t cd1 = __builtin_amdgcn_perm(du, cu, 0x07060302u); // (Cj1,Dj1)
                        int j = lc2 * 8 + 2 * u;
                        z[j]     = dot2f(ab0, rec.y, dot2f(cd0, rec.z, z[j]));
                        z[j + 1] = dot2f(ab1, rec.y, dot2f(cd1, rec.z, z[j + 1]));
                    }
                }
            }
            if (n > CAP) {                       // ultra-rare overflow path
                if (pass == 0) { oc = *ovf_cnt; if (oc > OVFMAX) oc = OVFMAX; }
                for (int o = 0; o < oc; ++o) {
                    uint4 rec = ovf[o];
                    if ((int)(rec.x >> 10) != r) continue;
                    int cell = (int)(rec.x & 1023);
                    if (pass == 0) {
                        float2 sx = __half22float2(*(__half2*)&rec.w);
                        eacc += sx.y;
                    }
                    #pragma unroll
                    for (int lc2 = 0; lc2 < 2; ++lc2) {
                        const uint4* base = tbl4 + (2 * q + lc2) * NPTS + cell;
                        uint4 A = base[0];
                        uint4 B = base[1];
                        uint4 C = base[TGP];
                        uint4 D = base[TGP + 1];
                        #pragma unroll
                        for (int u = 0; u < 4; ++u) {
                            uint32_t au = (&A.x)[u], bu = (&B.x)[u], cu = (&C.x)[u], du = (&D.x)[u];
                            uint32_t ab0 = __builtin_amdgcn_perm(bu, au, 0x05040100u);
                            uint32_t ab1 = __builtin_amdgcn_perm(bu, au, 0x07060302u);
                            uint32_t cd0 = __builtin_amdgcn_perm(du, cu, 0x05040100u);
                            uint32_t cd1 = __builtin_amdgcn_perm(du, cu, 0x07060302u);
                            int j = lc2 * 8 + 2 * u;
                            z[j]     = dot2f(ab0, rec.y, dot2f(cd0, rec.z, z[j]));
                            z[j + 1] = dot2f(ab1, rec.y, dot2f(cd1, rec.z, z[j + 1]));
                        }
                    }
                }
            }
            #pragma unroll
            for (int j = 0; j < 16; ++j)
                pp = fmaf(v2s[pass * 64 + q * 16 + j], fast_tanh(z[j]), pp);
        }
    }
    if (r < 0) return;                           // no barriers past this point
    pp += __shfl_xor(pp, 1);
    pp += __shfl_xor(pp, 2);                 // all 4 lanes hold the full sum
    // ---- finalize v + consumption scatter ----
    float em = eacc / (float)(n > 0 ? n : 1);
    float bv = softplus_f(pp + c2[0]);
    float k  = __expf(log_k[r] * 2.302585092994046f);
    float vr = k * em * bv;
    if (q == 0) v_out[r] = vr;
    float w = vr * DT;
    for (int e = q; e < nmain; e += 4) {
        uint4 rec = rrec[e];
        float2 sx = __half22float2(*(__half2*)&rec.w);
        atomicAdd(&tot[rec.x >> 10], sx.x * w);
    }
    if (n > CAP && q == 0) {
        for (int o = 0; o < oc; ++o) {
            if ((int)(ovf[o].x >> 10) != r) continue;
            float2 sx = __half22float2(*(__half2*)&ovf[o].w);
            atomicAdd(&tot[ovf2[o].x], sx.x * w);
        }
    }
}

// Slot-parallel scale+scatter: 8 lanes per reaction, lane l owns rec slot l.
__global__ void __launch_bounds__(256)
scale8(const int* __restrict__ cnt, const int* __restrict__ pcnt,
       const uint4* __restrict__ recs, const uint2* __restrict__ precs,
       const uint4* __restrict__ ovf, const uint2* __restrict__ ovf2,
       const uint4* __restrict__ povf,
       const int* __restrict__ ovf_cnt, const int* __restrict__ povf_cnt,
       const float* __restrict__ x, const float* __restrict__ tot,
       const float* __restrict__ v, float* __restrict__ out) {
    int t = blockIdx.x * blockDim.x + threadIdx.x;
    int r = t >> 3, l = t & 7;
    if (r >= N_RXN) return;
    int n = cnt[r];
    int nmain = n < CAP ? n : CAP;
    uint4 rec = recs[(size_t)r * CAP + l];        // coalesced: 8 lanes = 128B line
    uint32_t m = rec.x >> 10;
    float sto = 0.0f;
    float cand = 1.0f;
    if (l < nmain) {
        float2 sx = __half22float2(*(__half2*)&rec.w);
        sto = sx.x;
        float tc = tot[m];
        if (tc > 1e-12f) cand = fminf(x[m * 8 + 3] / tc, 1.0f);
    }
    int oc = 0;
    if (n > CAP) {                                 // rare overflow: lane 0 serial
        oc = *ovf_cnt; if (oc > OVFMAX) oc = OVFMAX;
        if (l == 0) {
            for (int o = 0; o < oc; ++o) {
                if ((int)(ovf[o].x >> 10) != r) continue;
                uint32_t mm = ovf2[o].x;
                float tc = tot[mm];
                if (tc > 1e-12f) cand = fminf(cand, fminf(x[mm * 8 + 3] / tc, 1.0f));
            }
        }
    }
    cand = fminf(cand, __shfl_xor(cand, 1));
    cand = fminf(cand, __shfl_xor(cand, 2));
    cand = fminf(cand, __shfl_xor(cand, 4));       // all 8 lanes: group min
    float vr = v[r] * cand;
    if (l < nmain) atomicAdd(&out[m], -sto * vr);  // substrate contribution
    if (n > CAP && l == 0) {
        for (int o = 0; o < oc; ++o) {
            if ((int)(ovf[o].x >> 10) != r) continue;
            float2 sx = __half22float2(*(__half2*)&ovf[o].w);
            atomicAdd(&out[ovf2[o].x], -sx.x * vr);
        }
    }
    int np = pcnt[r];
    int npm = np < CAP ? np : CAP;
    if (l < npm) {
        uint2 pr = precs[(size_t)r * CAP + l];     // coalesced: 8 lanes = 64B
        atomicAdd(&out[pr.x], __uint_as_float(pr.y) * vr);
    }
    if (np > CAP && l == 0) {
        int oc2 = *povf_cnt; if (oc2 > OVFMAX) oc2 = OVFMAX;
        for (int o = 0; o < oc2; ++o) {
            if ((int)povf[o].x != r) continue;
            atomicAdd(&out[povf[o].y], __uint_as_float(povf[o].z) * vr);
        }
    }
}

extern "C" void kernel_launch(void* const* d_in, const int* in_sizes, int n_in,
                              void* d_out, int out_size, void* d_ws, size_t ws_size,
                              hipStream_t stream) {
    const float* x        = (const float*)d_in[0];
    const int*   met_sub  = (const int*)d_in[1];
    const int*   rxn_sub  = (const int*)d_in[2];
    const float* sto_sub  = (const float*)d_in[3];
    const int*   met_prod = (const int*)d_in[4];
    const int*   rxn_prod = (const int*)d_in[5];
    const float* sto_prod = (const float*)d_in[6];
    const float* W1       = (const float*)d_in[7];
    const float* b1       = (const float*)d_in[8];
    const float* W2       = (const float*)d_in[9];
    const float* b2       = (const float*)d_in[10];
    const float* V1       = (const float*)d_in[11];
    const float* c1       = (const float*)d_in[12];
    const float* V2       = (const float*)d_in[13];
    const float* c2       = (const float*)d_in[14];
    const float* log_k    = (const float*)d_in[15];

    uint4* recs    = (uint4*)d_ws;                    // N_RXN*CAP        25.6 MB
    uint2* precs   = (uint2*)(recs + (size_t)N_RXN * CAP);   // N_RXN*CAP 12.8 MB
    uint4* ovf     = (uint4*)(precs + (size_t)N_RXN * CAP);  // OVFMAX
    uint2* ovf2    = (uint2*)(ovf + OVFMAX);
    uint4* povf    = (uint4*)(ovf2 + OVFMAX);
    int*   cnt     = (int*)(povf + OVFMAX);           // ---- zero region start ----
    int*   pcnt    = cnt + N_RXN;
    float* tot     = (float*)(pcnt + N_RXN);
    int*   ovf_cnt = (int*)(tot + N_MET);
    int*   povf_cnt = ovf_cnt + 1;                    // ---- zero region end ----
    float* v       = (float*)(povf_cnt + 3);
    uint32_t* TG   = (uint32_t*)(v + N_RXN);          // CCH*NPTS uint4 = 73,984 B
    float* outf = (float*)d_out;

    size_t zbytes = (size_t)(2 * N_RXN + N_MET + 4) * 4;   // cnt,pcnt,tot,counters
    hipMemsetAsync(cnt, 0, zbytes, stream);
    hipMemsetAsync(outf, 0, (size_t)N_MET * 4, stream);

    prep_all<<<NPTS + NBS8, 256, 0, stream>>>(
        W1, b1, W2, b2, V1, (__half*)TG,
        rxn_sub, met_sub, sto_sub, x,
        cnt, recs, ovf, ovf2, ovf_cnt);
    rxn_quad<<<PBLK + NGRP, RSB, 0, stream>>>(
        cnt, recs, ovf, ovf2, ovf_cnt, TG,
        c1, V2, c2, log_k,
        rxn_prod, met_prod, sto_prod,
        pcnt, precs, povf, povf_cnt,
        v, tot);
    scale8<<<((size_t)N_RXN * 8 + 255) / 256, 256, 0, stream>>>(
        cnt, pcnt, recs, precs, ovf, ovf2, povf, ovf_cnt, povf_cnt,
        x, tot, v, outf);
}

// Round 14
// 222.770 us; speedup vs baseline: 1.0247x; 1.0037x over previous
//
#include <hip/hip_runtime.h>
#include <hip/hip_fp16.h>
#include <cmath>
#include <cstdint>

#define N_MET   100000
#define N_RXN   200000
#define E_SUB   400000
#define E_PROD  400000
#define HIDDEN  128
#define MSG_DIM 64
#define DT      0.01f
#define TGRID   16                     // cells per axis
#define TGP     17                     // points per axis
#define NPTS    (TGP * TGP)            // 289
#define CCH     16                     // uint4 chunk-regions per point (128 dims)
#define HCH     8                      // chunks staged per pass (64 dims)
#define RPB     128                    // reactions per block (4 lanes/rxn)
#define RSB     512                    // threads per block
#define NGRP    ((N_RXN + RPB - 1) / RPB)   // 1563 rxn blocks
#define CAP     8                      // fixed bucket capacity per reaction
#define OVFMAX  4096
#define NBS8    ((E_SUB / 8 + 255) / 256)       // 196 sub-scatter blocks (8 edges/thr)
#define NZB     (((N_MET / 4) * 2 + 255) / 256) // 196 zero blocks (tot+out, float4)
#define PBLK    ((E_PROD / 4 + RSB - 1) / RSB)  // 196 prod blocks in rxn launch

typedef _Float16 h2v __attribute__((ext_vector_type(2)));

__device__ __forceinline__ float dot2f(uint32_t a, uint32_t b, float c) {
#if __has_builtin(__builtin_amdgcn_fdot2)
    return __builtin_amdgcn_fdot2(__builtin_bit_cast(h2v, a),
                                  __builtin_bit_cast(h2v, b), c, false);
#else
    float2 fa = __half22float2(*(__half2*)&a);
    float2 fb = __half22float2(*(__half2*)&b);
    return fmaf(fa.x, fb.x, fmaf(fa.y, fb.y, c));
#endif
}

__device__ __forceinline__ float fast_tanh(float x) {
    float t = __expf(2.0f * x);
    return 1.0f - 2.0f * __builtin_amdgcn_rcpf(t + 1.0f);
}

__device__ __forceinline__ float softplus_f(float x) {
    return (x > 20.0f) ? x : log1pf(__expf(x));
}

// Heterogeneous blocks:
//   blocks [0, NPTS)                  : table build (threads<128 active)
//   blocks [NPTS, NPTS+NBS8)          : substrate edge scatter, 8 edges/thread
//   blocks [NPTS+NBS8, +NZB)          : zero tot + out (float4) — replaces a
//                                       hipMemsetAsync graph node. Safe: no
//                                       block in this kernel reads tot/out.
// Table layout == LDS layout (identity staging): half ((c*NPTS+p)*8 + h).
__global__ void __launch_bounds__(256)
prep_all(const float* __restrict__ W1, const float* __restrict__ b1,
         const float* __restrict__ W2, const float* __restrict__ b2,
         const float* __restrict__ V1, __half* __restrict__ TGh,
         const int* __restrict__ rxn_sub, const int* __restrict__ met_sub,
         const float* __restrict__ sto_sub, const float* __restrict__ x,
         int* __restrict__ cnt,
         uint4* __restrict__ recs,
         uint4* __restrict__ ovf, uint2* __restrict__ ovf2,
         int* __restrict__ ovf_cnt,
         float* __restrict__ tot, float* __restrict__ out) {
    __shared__ float h_s[HIDDEN];
    __shared__ float msg_s[MSG_DIM];
    int bid = blockIdx.x;
    int tid = threadIdx.x;
    if (bid < NPTS) {
        // ---- table build ----
        int p = bid;
        int ia = p / TGP, ib = p % TGP;
        float a = (float)ia * (1.0f / TGRID);
        float b = 0.5f + (float)ib * (1.0f / TGRID);
        if (tid < HIDDEN)
            h_s[tid] = tanhf(fmaf(a, W1[tid], fmaf(b, W1[HIDDEN + tid], b1[tid])));
        __syncthreads();
        if (tid < MSG_DIM) {
            float acc = b2[tid];
            #pragma unroll 4
            for (int j = 0; j < HIDDEN; ++j)
                acc = fmaf(h_s[j], W2[j * MSG_DIM + tid], acc);
            msg_s[tid] = acc;
        }
        __syncthreads();
        if (tid < HIDDEN) {
            float g = 0.0f;
            #pragma unroll 4
            for (int m = 0; m < MSG_DIM; ++m)
                g = fmaf(msg_s[m], V1[m * HIDDEN + tid], g);
            int c = tid >> 3;
            int h = tid & 7;
            TGh[((size_t)(c * NPTS + p) * 8) + h] = __float2half(g);
        }
        return;
    }
    if (bid >= NPTS + NBS8) {
        // ---- zero tot + out (float4 stores) ----
        int i = (bid - NPTS - NBS8) * 256 + tid;
        const int q4 = N_MET / 4;                 // 25,000
        float4 zz = make_float4(0.f, 0.f, 0.f, 0.f);
        if (i < q4)           ((float4*)tot)[i] = zz;
        else if (i < 2 * q4)  ((float4*)out)[i - q4] = zz;
        return;
    }
    // ---- substrate scatter: 8 edges per thread, vectorized reads ----
    int i8 = (bid - NPTS) * 256 + tid;            // 8-edge group index
    if (i8 >= E_SUB / 8) return;
    int4   rr0 = ((const int4*)rxn_sub)[2 * i8],     rr1 = ((const int4*)rxn_sub)[2 * i8 + 1];
    int4   mm0 = ((const int4*)met_sub)[2 * i8],     mm1 = ((const int4*)met_sub)[2 * i8 + 1];
    float4 ss0 = ((const float4*)sto_sub)[2 * i8],   ss1 = ((const float4*)sto_sub)[2 * i8 + 1];
    #pragma unroll
    for (int u = 0; u < 8; ++u) {
        int r  = (u < 4) ? (&rr0.x)[u] : (&rr1.x)[u - 4];
        int me = (u < 4) ? (&mm0.x)[u] : (&mm1.x)[u - 4];
        float se  = (u < 4) ? (&ss0.x)[u] : (&ss1.x)[u - 4];
        float ae  = x[me * 8 + 3];
        float ext = x[me * 8 + 4];
        float fa = ae * (float)TGRID;
        float fb = (se - 0.5f) * (float)TGRID;
        int ia = (int)fa; ia = ia < 0 ? 0 : (ia > TGRID - 1 ? TGRID - 1 : ia);
        int ib = (int)fb; ib = ib < 0 ? 0 : (ib > TGRID - 1 ? TGRID - 1 : ib);
        float wa = fa - (float)ia, wb = fb - (float)ib;
        float ua = 1.0f - wa, ub = 1.0f - wb;
        __half2 hA = __floats2half2_rn(ua * ub, ua * wb);   // w00, w01
        __half2 hB = __floats2half2_rn(wa * ub, wa * wb);   // w10, w11
        __half2 hS = __floats2half2_rn(se, ext);            // sto, ext
        int cell = ia * TGP + ib;                            // point space, <= 288
        int slot = atomicAdd(&cnt[r], 1);
        uint4 rec;
        rec.y = *(uint32_t*)&hA;
        rec.z = *(uint32_t*)&hB;
        rec.w = *(uint32_t*)&hS;
        if (slot < CAP) {
            rec.x = (uint32_t)cell | ((uint32_t)me << 10);
            recs[(size_t)r * CAP + slot] = rec;
        } else {
            int o = atomicAdd(ovf_cnt, 1);
            if (o < OVFMAX) {
                rec.x = (uint32_t)cell | ((uint32_t)r << 10);
                ovf[o] = rec;
                ovf2[o] = make_uint2((uint32_t)me, 0u);
            }
        }
    }
}

// Heterogeneous launch:
//   blocks [0, PBLK)        : product-CSR build (4 edges/thread)
//   blocks [PBLK, +NGRP)    : reaction compute, TWO-PASS half-table.
// Pass p stages chunks 8p..8p+7 (37 KB) into ONE LDS buffer; lane q owns
// local chunks {2q, 2q+1} = dims 64p+16q .. +15 (z[16]/lane). 3 blocks/CU.
__global__ void __launch_bounds__(RSB, 6)
rxn_quad(const int* __restrict__ cnt, const uint4* __restrict__ recs,
         const uint4* __restrict__ ovf, const uint2* __restrict__ ovf2,
         const int* __restrict__ ovf_cnt, const uint32_t* __restrict__ TG,
         const float* __restrict__ c1, const float* __restrict__ V2,
         const float* __restrict__ c2, const float* __restrict__ log_k,
         const int* __restrict__ rxn_prod, const int* __restrict__ met_prod,
         const float* __restrict__ sto_prod,
         int* __restrict__ pcnt, uint2* __restrict__ precs,
         uint4* __restrict__ povf, int* __restrict__ povf_cnt,
         float* __restrict__ v_out, float* __restrict__ tot) {
    __shared__ uint4 tbl4[HCH * NPTS];            // 36,992 B half-table
    __shared__ float c1s[HIDDEN];
    __shared__ float v2s[HIDDEN];
    __shared__ int sorted_s[RPB];
    __shared__ int h16[16];
    int t = threadIdx.x;
    if (blockIdx.x < PBLK) {
        // ---- product scatter: 4 edges per thread ----
        int i4 = blockIdx.x * RSB + t;            // int4 index
        if (i4 >= E_PROD / 4) return;
        int4   rr = ((const int4*)rxn_prod)[i4];
        int4   mm = ((const int4*)met_prod)[i4];
        float4 ss = ((const float4*)sto_prod)[i4];
        #pragma unroll
        for (int u = 0; u < 4; ++u) {
            int r  = (&rr.x)[u];
            int me = (&mm.x)[u];
            float sp = (&ss.x)[u];
            int slot = atomicAdd(&pcnt[r], 1);
            if (slot < CAP) {
                precs[(size_t)r * CAP + slot] = make_uint2((uint32_t)me, __float_as_uint(sp));
            } else {
                int o = atomicAdd(povf_cnt, 1);
                if (o < OVFMAX)
                    povf[o] = make_uint4((uint32_t)r, (uint32_t)me, __float_as_uint(sp), 0u);
            }
        }
        return;
    }
    int rbase = (blockIdx.x - PBLK) * RPB;
    int nval = N_RXN - rbase; if (nval > RPB) nval = RPB;

    // ---- in-block counting sort by edge count ----
    if (t < 16) h16[t] = 0;
    if (t < HIDDEN) { c1s[t] = c1[t]; v2s[t] = V2[t]; }
    __syncthreads();
    int n1 = -1, k1 = 0;
    if (t < nval) {
        n1 = cnt[rbase + t];
        k1 = n1 > 15 ? 15 : n1;
        atomicAdd(&h16[k1], 1);
    }
    __syncthreads();
    if (t == 0) {
        int acc = 0;
        #pragma unroll
        for (int b = 0; b < 16; ++b) { int c = h16[b]; h16[b] = acc; acc += c; }
    }
    __syncthreads();
    if (n1 >= 0) sorted_s[atomicAdd(&h16[k1], 1)] = t;
    // (sorted_s reads happen after the pass-0 post-staging barrier below)

    int slot = t >> 2, q = t & 3;
    int r = -1, n = 0, nmain = 0, oc = 0;
    const uint4* rrec = nullptr;
    float pp = 0.0f, eacc = 0.0f;

    #pragma unroll 1
    for (int pass = 0; pass < 2; ++pass) {
        if (pass) __syncthreads();               // pass-0 reads of tbl4 done
        // ---- stage this pass's half-table (identity-coalesced) ----
        {
            const uint4* src = (const uint4*)TG + pass * (HCH * NPTS);
            for (int i = t; i < HCH * NPTS; i += RSB) tbl4[i] = src[i];
        }
        __syncthreads();                         // table (and sorted_s) ready
        if (pass == 0 && slot < nval) {
            r = rbase + sorted_s[slot];
            n = cnt[r];
            nmain = n < CAP ? n : CAP;
            rrec = recs + (size_t)r * CAP;
        }
        if (r >= 0) {
            float z[16];
            #pragma unroll
            for (int j = 0; j < 16; ++j) z[j] = c1s[pass * 64 + q * 16 + j];
            for (int e = 0; e < nmain; ++e) {
                uint4 rec = rrec[e];             // 4 lanes: same line (broadcast)
                int cell = (int)(rec.x & 1023);
                if (pass == 0) {
                    float2 sx = __half22float2(*(__half2*)&rec.w);
                    eacc += sx.y;
                }
                #pragma unroll
                for (int lc2 = 0; lc2 < 2; ++lc2) {
                    const uint4* base = tbl4 + (2 * q + lc2) * NPTS + cell;
                    uint4 A = base[0];
                    uint4 B = base[1];
                    uint4 C = base[TGP];
                    uint4 D = base[TGP + 1];
                    #pragma unroll
                    for (int u = 0; u < 4; ++u) {
                        uint32_t au = (&A.x)[u], bu = (&B.x)[u], cu = (&C.x)[u], du = (&D.x)[u];
                        uint32_t ab0 = __builtin_amdgcn_perm(bu, au, 0x05040100u); // (Aj ,Bj )
                        uint32_t ab1 = __builtin_amdgcn_perm(bu, au, 0x07060302u); // (Aj1,Bj1)
                        uint32_t cd0 = __builtin_amdgcn_perm(du, cu, 0x05040100u); // (Cj ,Dj )
                        uint32_t cd1 = __builtin_amdgcn_perm(du, cu, 0x07060302u); // (Cj1,Dj1)
                        int j = lc2 * 8 + 2 * u;
                        z[j]     = dot2f(ab0, rec.y, dot2f(cd0, rec.z, z[j]));
                        z[j + 1] = dot2f(ab1, rec.y, dot2f(cd1, rec.z, z[j + 1]));
                    }
                }
            }
            if (n > CAP) {                       // ultra-rare overflow path
                if (pass == 0) { oc = *ovf_cnt; if (oc > OVFMAX) oc = OVFMAX; }
                for (int o = 0; o < oc; ++o) {
                    uint4 rec = ovf[o];
                    if ((int)(rec.x >> 10) != r) continue;
                    int cell = (int)(rec.x & 1023);
                    if (pass == 0) {
                        float2 sx = __half22float2(*(__half2*)&rec.w);
                        eacc += sx.y;
                    }
                    #pragma unroll
                    for (int lc2 = 0; lc2 < 2; ++lc2) {
                        const uint4* base = tbl4 + (2 * q + lc2) * NPTS + cell;
                        uint4 A = base[0];
                        uint4 B = base[1];
                        uint4 C = base[TGP];
                        uint4 D = base[TGP + 1];
                        #pragma unroll
                        for (int u = 0; u < 4; ++u) {
                            uint32_t au = (&A.x)[u], bu = (&B.x)[u], cu = (&C.x)[u], du = (&D.x)[u];
                            uint32_t ab0 = __builtin_amdgcn_perm(bu, au, 0x05040100u);
                            uint32_t ab1 = __builtin_amdgcn_perm(bu, au, 0x07060302u);
                            uint32_t cd0 = __builtin_amdgcn_perm(du, cu, 0x05040100u);
                            uint32_t cd1 = __builtin_amdgcn_perm(du, cu, 0x07060302u);
                            int j = lc2 * 8 + 2 * u;
                            z[j]     = dot2f(ab0, rec.y, dot2f(cd0, rec.z, z[j]));
                            z[j + 1] = dot2f(ab1, rec.y, dot2f(cd1, rec.z, z[j + 1]));
                        }
                    }
                }
            }
            #pragma unroll
            for (int j = 0; j < 16; ++j)
                pp = fmaf(v2s[pass * 64 + q * 16 + j], fast_tanh(z[j]), pp);
        }
    }
    if (r < 0) return;                           // no barriers past this point
    pp += __shfl_xor(pp, 1);
    pp += __shfl_xor(pp, 2);                 // all 4 lanes hold the full sum
    // ---- finalize v + consumption scatter ----
    float em = eacc / (float)(n > 0 ? n : 1);
    float bv = softplus_f(pp + c2[0]);
    float k  = __expf(log_k[r] * 2.302585092994046f);
    float vr = k * em * bv;
    if (q == 0) v_out[r] = vr;
    float w = vr * DT;
    for (int e = q; e < nmain; e += 4) {
        uint4 rec = rrec[e];
        float2 sx = __half22float2(*(__half2*)&rec.w);
        atomicAdd(&tot[rec.x >> 10], sx.x * w);
    }
    if (n > CAP && q == 0) {
        for (int o = 0; o < oc; ++o) {
            if ((int)(ovf[o].x >> 10) != r) continue;
            float2 sx = __half22float2(*(__half2*)&ovf[o].w);
            atomicAdd(&tot[ovf2[o].x], sx.x * w);
        }
    }
}

// Slot-parallel scale+scatter: 8 lanes per reaction, lane l owns rec slot l.
// recs load predicated on l<nmain: cuts the dead-slot stream (~18 MB).
__global__ void __launch_bounds__(256)
scale8(const int* __restrict__ cnt, const int* __restrict__ pcnt,
       const uint4* __restrict__ recs, const uint2* __restrict__ precs,
       const uint4* __restrict__ ovf, const uint2* __restrict__ ovf2,
       const uint4* __restrict__ povf,
       const int* __restrict__ ovf_cnt, const int* __restrict__ povf_cnt,
       const float* __restrict__ x, const float* __restrict__ tot,
       const float* __restrict__ v, float* __restrict__ out) {
    int t = blockIdx.x * blockDim.x + threadIdx.x;
    int r = t >> 3, l = t & 7;
    if (r >= N_RXN) return;
    int n = cnt[r];
    int nmain = n < CAP ? n : CAP;
    uint32_t m = 0;
    float sto = 0.0f;
    float cand = 1.0f;
    if (l < nmain) {
        uint4 rec = recs[(size_t)r * CAP + l];    // only live slots fetched
        m = rec.x >> 10;
        float2 sx = __half22float2(*(__half2*)&rec.w);
        sto = sx.x;
        float tc = tot[m];
        if (tc > 1e-12f) cand = fminf(x[m * 8 + 3] / tc, 1.0f);
    }
    int oc = 0;
    if (n > CAP) {                                 // rare overflow: lane 0 serial
        oc = *ovf_cnt; if (oc > OVFMAX) oc = OVFMAX;
        if (l == 0) {
            for (int o = 0; o < oc; ++o) {
                if ((int)(ovf[o].x >> 10) != r) continue;
                uint32_t mm = ovf2[o].x;
                float tc = tot[mm];
                if (tc > 1e-12f) cand = fminf(cand, fminf(x[mm * 8 + 3] / tc, 1.0f));
            }
        }
    }
    cand = fminf(cand, __shfl_xor(cand, 1));
    cand = fminf(cand, __shfl_xor(cand, 2));
    cand = fminf(cand, __shfl_xor(cand, 4));       // all 8 lanes: group min
    float vr = v[r] * cand;
    if (l < nmain) atomicAdd(&out[m], -sto * vr);  // substrate contribution
    if (n > CAP && l == 0) {
        for (int o = 0; o < oc; ++o) {
            if ((int)(ovf[o].x >> 10) != r) continue;
            float2 sx = __half22float2(*(__half2*)&ovf[o].w);
            atomicAdd(&out[ovf2[o].x], -sx.x * vr);
        }
    }
    int np = pcnt[r];
    int npm = np < CAP ? np : CAP;
    if (l < npm) {
        uint2 pr = precs[(size_t)r * CAP + l];     // coalesced: live slots only
        atomicAdd(&out[pr.x], __uint_as_float(pr.y) * vr);
    }
    if (np > CAP && l == 0) {
        int oc2 = *povf_cnt; if (oc2 > OVFMAX) oc2 = OVFMAX;
        for (int o = 0; o < oc2; ++o) {
            if ((int)povf[o].x != r) continue;
            atomicAdd(&out[povf[o].y], __uint_as_float(povf[o].z) * vr);
        }
    }
}

extern "C" void kernel_launch(void* const* d_in, const int* in_sizes, int n_in,
                              void* d_out, int out_size, void* d_ws, size_t ws_size,
                              hipStream_t stream) {
    const float* x        = (const float*)d_in[0];
    const int*   met_sub  = (const int*)d_in[1];
    const int*   rxn_sub  = (const int*)d_in[2];
    const float* sto_sub  = (const float*)d_in[3];
    const int*   met_prod = (const int*)d_in[4];
    const int*   rxn_prod = (const int*)d_in[5];
    const float* sto_prod = (const float*)d_in[6];
    const float* W1       = (const float*)d_in[7];
    const float* b1       = (const float*)d_in[8];
    const float* W2       = (const float*)d_in[9];
    const float* b2       = (const float*)d_in[10];
    const float* V1       = (const float*)d_in[11];
    const float* c1       = (const float*)d_in[12];
    const float* V2       = (const float*)d_in[13];
    const float* c2       = (const float*)d_in[14];
    const float* log_k    = (const float*)d_in[15];

    // ---- memset region (contiguous, 16B-multiple): cnt, pcnt, counters ----
    int*   cnt      = (int*)d_ws;                     // N_RXN
    int*   pcnt     = cnt + N_RXN;                    // N_RXN
    int*   ovf_cnt  = pcnt + N_RXN;                   // 1
    int*   povf_cnt = ovf_cnt + 1;                    // 1 (+2 pad)
    // ---- zeroed inside prep_all ----
    float* tot      = (float*)(povf_cnt + 3);         // N_MET
    // ---- fully overwritten every launch ----
    float* v        = tot + N_MET;                    // N_RXN
    uint4* ovf      = (uint4*)(v + N_RXN);            // OVFMAX (16B aligned)
    uint2* ovf2     = (uint2*)(ovf + OVFMAX);         // OVFMAX
    uint4* povf     = (uint4*)(ovf2 + OVFMAX);        // OVFMAX
    uint4* recs     = povf + OVFMAX;                  // N_RXN*CAP  25.6 MB
    uint2* precs    = (uint2*)(recs + (size_t)N_RXN * CAP);  // N_RXN*CAP
    uint32_t* TG    = (uint32_t*)(precs + (size_t)N_RXN * CAP); // 73,984 B
    float* outf = (float*)d_out;

    size_t zbytes = (size_t)(2 * N_RXN + 4) * 4;      // cnt, pcnt, counters
    hipMemsetAsync(cnt, 0, zbytes, stream);

    prep_all<<<NPTS + NBS8 + NZB, 256, 0, stream>>>(
        W1, b1, W2, b2, V1, (__half*)TG,
        rxn_sub, met_sub, sto_sub, x,
        cnt, recs, ovf, ovf2, ovf_cnt,
        tot, outf);
    rxn_quad<<<PBLK + NGRP, RSB, 0, stream>>>(
        cnt, recs, ovf, ovf2, ovf_cnt, TG,
        c1, V2, c2, log_k,
        rxn_prod, met_prod, sto_prod,
        pcnt, precs, povf, povf_cnt,
        v, tot);
    scale8<<<((size_t)N_RXN * 8 + 255) / 256, 256, 0, stream>>>(
        cnt, pcnt, recs, precs, ovf, ovf2, povf, ovf_cnt, povf_cnt,
        x, tot, v, outf);
}